// Round 3
// baseline (492.517 us; speedup 1.0000x reference)
//
#include <hip/hip_runtime.h>
#include <math.h>

// MemoryUnit: fn=l2norm(feature), mn=l2norm(memory), S=fn.mn^T -> softmax ->
// hardshrink(0.0005) -> softmax -> w ; mem_feat = w @ memory.
// Round 8: T3-minimum 2-phase pipeline with ONLY standard __syncthreads().
//  (Rounds 6/7 used a raw lgkm-only barrier and both benches died with no
//   signal; this round reverts to the verified barrier discipline and keeps
//   the pipelining via issue-after-barrier / drain-at-end-of-compute.)
//  - A/W staging double-buffered via cp_async (global_load_lds): tile t+1 is
//    issued RIGHT AFTER the mid __syncthreads (Bsm-visibility barrier) of
//    iter t, and drains at the END-of-iter __syncthreads -- i.e. hidden under
//    the whole ds_read+MFMA phase instead of draining at issue (baseline).
//  - B tile prefetched into registers the same way (issued after mid barrier,
//    consumed next iteration; the end-of-iter __syncthreads drains it under
//    the compute phase).
//  - OOB predicates are address-clamps (row 0): garbage products land only in
//    S columns >= M_DIM (masked -INF in softmax) / multiply exact-0 W cols.

#define D_DIM 32768
#define B_DIM 256
#define M_DIM 2000
#define M_PAD 2048
#define NS1 16
#define KSLAB (D_DIM / NS1)   // 2048
#define LAM 0.0005f
#define LDB 72                // padded LDS stride (ushorts) for gemm1 B tile

typedef __attribute__((ext_vector_type(8))) short bf16x8;   // 8 bf16 = 4 VGPR
typedef __attribute__((ext_vector_type(4))) float f32x4;

#define GLOBAL_AS __attribute__((address_space(1)))
#define LDS_AS __attribute__((address_space(3)))

__device__ __forceinline__ void cp_async16(const void* g, void* l) {
  // 64 lanes x 16B -> LDS base + lane*16 (wave-uniform lds base required)
  __builtin_amdgcn_global_load_lds((const GLOBAL_AS unsigned int*)g,
                                   (LDS_AS unsigned int*)l, 16, 0, 0);
}

__device__ __forceinline__ unsigned short f2bf(float f) {
  union { float f; unsigned u; } v; v.f = f;
  unsigned r = v.u + 0x7FFFu + ((v.u >> 16) & 1u);  // RNE
  return (unsigned short)(r >> 16);
}

// ---------------- zero (for rnm_sq atomics) ----------------
__global__ __launch_bounds__(256) void zero_kernel(float* __restrict__ p, int n) {
  int i = blockIdx.x * 256 + threadIdx.x;
  if (i < n) p[i] = 0.f;
}

// ---------------- prep feature: fp32 -> bf16 + 1/max(||x||,eps) ----------------
__global__ __launch_bounds__(256) void prep_feat_kernel(const float* __restrict__ src,
                                                        unsigned short* __restrict__ dst,
                                                        float* __restrict__ rn_inv) {
  const size_t row = blockIdx.x;
  const int t = threadIdx.x;
  const float4* p = (const float4*)(src + row * (size_t)D_DIM);
  ushort4* q = (ushort4*)(dst + row * (size_t)D_DIM);
  float s = 0.f;
  for (int i = t; i < D_DIM / 4; i += 256) {
    float4 v = p[i];
    s = fmaf(v.x, v.x, s); s = fmaf(v.y, v.y, s);
    s = fmaf(v.z, v.z, s); s = fmaf(v.w, v.w, s);
    ushort4 b; b.x = f2bf(v.x); b.y = f2bf(v.y); b.z = f2bf(v.z); b.w = f2bf(v.w);
    q[i] = b;
  }
  #pragma unroll
  for (int off = 32; off > 0; off >>= 1) s += __shfl_down(s, off, 64);
  __shared__ float partial[4];
  if ((t & 63) == 0) partial[t >> 6] = s;
  __syncthreads();
  if (t == 0) {
    float tt = partial[0] + partial[1] + partial[2] + partial[3];
    rn_inv[row] = 1.0f / fmaxf(sqrtf(tt), 1e-12f);
  }
}

// ---------------- fused GEMM1 + memory norm (2-phase pipelined) ----------------
// Grid (32 m-tiles, 16 k-splits). A = F16 (cp_async16, swizzled unpadded LDS,
// double-buffered); B = memory fp32 prefetched to regs -> cvt bf16 -> padded
// LDS; sumsq accumulated. All barriers are full __syncthreads().
__global__ __launch_bounds__(256, 2) void gemm1_fused(const unsigned short* __restrict__ F16,
                                                      const float* __restrict__ mem,
                                                      float* __restrict__ Spart,
                                                      float* __restrict__ rnm_sq) {
  __shared__ __align__(16) unsigned short Asm[2][256 * 64];   // 64 KB dbuf, swizzled
  __shared__ __align__(16) unsigned short Bsm[64 * LDB];      // 9 KB, padded
  const int t = threadIdx.x;
  const int m0 = blockIdx.x * 64;
  const int kbase = blockIdx.y * KSLAB;
  const int wid = t >> 6, lane = t & 63;
  const int lr = lane & 15, kq = lane >> 4;
  const int l8 = lane & 7, lrow = lane >> 3;

  // B staging: thread handles row (t>>2), 16 floats at col (t&3)*16
  const int brow = t >> 2;
  const int bcol = (t & 3) * 16;
  const int gm = m0 + brow;
  const bool bvalid = gm < M_DIM;
  // OOB rows clamped to row 0: products land in S columns >= M_DIM (masked in
  // softmax) and ss is discarded (atomicAdd guarded by bvalid).
  const float* Bg = mem + (size_t)(bvalid ? gm : 0) * D_DIM + kbase + bcol;

  const unsigned short* Ab = F16 + (size_t)(64 * wid + lrow) * D_DIM + kbase + (l8 ^ lrow) * 8;

  f32x4 acc[4][4] = {};
  float ss = 0.f;

  // prologue: stage tile 0 (exposed latency once; drains at iter-0 mid barrier
  // / the v-reg use in convert)
  #pragma unroll
  for (int i = 0; i < 8; i++)
    cp_async16(Ab + (size_t)(8 * i) * D_DIM, &Asm[0][(64 * wid + 8 * i) * 64]);
  float4 v[4];
  #pragma unroll
  for (int j = 0; j < 4; j++) v[j] = *(const float4*)(Bg + 4 * j);

  int cur = 0;
  const int NT = KSLAB / 64;          // 32
  for (int kt = 0; kt < NT; kt++) {
    // phase 1: convert current B regs -> Bsm (+ sumsq)
    #pragma unroll
    for (int j = 0; j < 4; j++) {
      ss = fmaf(v[j].x, v[j].x, ss); ss = fmaf(v[j].y, v[j].y, ss);
      ss = fmaf(v[j].z, v[j].z, ss); ss = fmaf(v[j].w, v[j].w, ss);
      ushort4 c; c.x = f2bf(v[j].x); c.y = f2bf(v[j].y);
      c.z = f2bf(v[j].z); c.w = f2bf(v[j].w);
      *(ushort4*)&Bsm[brow * LDB + bcol + 4 * j] = c;
    }
    __syncthreads();   // mid: Bsm visible; Asm[cur] complete (vmcnt drained);
                       // nothing else in flight at this point

    // phase 2a: issue next-tile prefetch AFTER the barrier so it drains at the
    // END-of-iter barrier -- hidden under the ds_read+MFMA phase below.
    float4 vn[4];
    if (kt + 1 < NT) {
      const int kk = (kt + 1) * 64;
      #pragma unroll
      for (int i = 0; i < 8; i++)
        cp_async16(Ab + kk + (size_t)(8 * i) * D_DIM, &Asm[cur ^ 1][(64 * wid + 8 * i) * 64]);
      #pragma unroll
      for (int j = 0; j < 4; j++) vn[j] = *(const float4*)(Bg + kk + 4 * j);
    }

    // phase 2b: compute from Asm[cur], Bsm
    bf16x8 bfr[2][4];
    #pragma unroll
    for (int h = 0; h < 2; h++)
      #pragma unroll
      for (int ni = 0; ni < 4; ni++)
        bfr[h][ni] = *(const bf16x8*)&Bsm[(ni * 16 + lr) * LDB + h * 32 + kq * 8];
    #pragma unroll
    for (int mi = 0; mi < 4; mi++) {
      #pragma unroll
      for (int h = 0; h < 2; h++) {
        const int sw = ((h * 4 + kq) ^ (lr & 7)) * 8;
        const bf16x8 af = *(const bf16x8*)&Asm[cur][(wid * 64 + mi * 16 + lr) * 64 + sw];
        #pragma unroll
        for (int ni = 0; ni < 4; ni++)
          acc[mi][ni] = __builtin_amdgcn_mfma_f32_16x16x32_bf16(af, bfr[h][ni], acc[mi][ni], 0, 0, 0);
      }
    }
    __syncthreads();   // end: prefetch drained (hidden under compute); all
                       // Bsm/Asm[cur] reads done before next iter's overwrite
    if (kt + 1 < NT) {
      #pragma unroll
      for (int j = 0; j < 4; j++) v[j] = vn[j];
    }
    cur ^= 1;
  }

  // sumsq: 4 threads share a row
  ss += __shfl_down(ss, 2, 4);
  ss += __shfl_down(ss, 1, 4);
  if ((t & 3) == 0 && bvalid) atomicAdd(&rnm_sq[gm], ss);

  // Spart[split][b][m]; C/D layout col=lane&15, row=(lane>>4)*4+j
  float* Sp = Spart + (size_t)blockIdx.y * (B_DIM * M_PAD);
  #pragma unroll
  for (int mi = 0; mi < 4; mi++) {
    const int b0 = wid * 64 + mi * 16 + kq * 4;
    #pragma unroll
    for (int ni = 0; ni < 4; ni++) {
      const int col = m0 + ni * 16 + lr;
      #pragma unroll
      for (int j = 0; j < 4; j++)
        Sp[(size_t)(b0 + j) * M_PAD + col] = acc[mi][ni][j];
    }
  }
}

// ---------------- softmax: reduce splits -> scale -> softmax -> shrink -> softmax ----
__device__ __forceinline__ float block_reduce(float x, bool is_max, float* red,
                                              int wid, int lane) {
  #pragma unroll
  for (int off = 32; off > 0; off >>= 1) {
    float o = __shfl_down(x, off, 64);
    x = is_max ? fmaxf(x, o) : (x + o);
  }
  __syncthreads();
  if (lane == 0) red[wid] = x;
  __syncthreads();
  return is_max ? fmaxf(fmaxf(red[0], red[1]), fmaxf(red[2], red[3]))
                : (red[0] + red[1] + red[2] + red[3]);
}

__global__ __launch_bounds__(256) void softmax_kernel(const float* __restrict__ Spart,
                                                      const float* __restrict__ rnf,
                                                      const float* __restrict__ rnm_sq,
                                                      float* __restrict__ wout,
                                                      unsigned short* __restrict__ wbf) {
  const int b = blockIdx.x;
  const int t = threadIdx.x;
  const int wid = t >> 6, lane = t & 63;
  const float sf = rnf[b];
  __shared__ float red[4];

  float v[8];
  #pragma unroll
  for (int g = 0; g < 2; g++) {
    const int mq = g * 1024 + 4 * t;             // quad base (quads never straddle M_DIM: 2000=4*500)
    f32x4 a = {0.f, 0.f, 0.f, 0.f};
    #pragma unroll
    for (int s = 0; s < NS1; s++)
      a += *(const f32x4*)&Spart[(size_t)s * (B_DIM * M_PAD) + (size_t)b * M_PAD + mq];
    #pragma unroll
    for (int j = 0; j < 4; j++) {
      const int m = mq + j;
      const float msc = 1.0f / fmaxf(sqrtf(rnm_sq[m]), 1e-12f);
      v[g * 4 + j] = (m < M_DIM) ? a[j] * (sf * msc) : -INFINITY;
    }
  }
  float mx = v[0];
  #pragma unroll
  for (int i = 1; i < 8; i++) mx = fmaxf(mx, v[i]);
  mx = block_reduce(mx, true, red, wid, lane);

  float e[8]; float sum = 0.f;
  #pragma unroll
  for (int i = 0; i < 8; i++) { e[i] = expf(v[i] - mx); sum += e[i]; }
  sum = block_reduce(sum, false, red, wid, lane);
  const float inv = 1.f / sum;

  float s2[8];
  #pragma unroll
  for (int i = 0; i < 8; i++) {
    float w1 = e[i] * inv;
    s2[i] = (w1 > LAM) ? w1 : 0.f;
  }
  float mx2 = 0.f;
  #pragma unroll
  for (int i = 0; i < 8; i++) mx2 = fmaxf(mx2, s2[i]);
  mx2 = block_reduce(mx2, true, red, wid, lane);

  float e2[8]; float sum2 = 0.f;
  #pragma unroll
  for (int g = 0; g < 2; g++)
    #pragma unroll
    for (int j = 0; j < 4; j++) {
      const int i = g * 4 + j;
      const int m = g * 1024 + 4 * t + j;
      e2[i] = (m < M_DIM) ? expf(s2[i] - mx2) : 0.f;
      sum2 += e2[i];
    }
  sum2 = block_reduce(sum2, false, red, wid, lane);
  const float inv2 = 1.f / sum2;

  #pragma unroll
  for (int g = 0; g < 2; g++) {
    const int mq = g * 1024 + 4 * t;
    float4 wq; ushort4 bq;
    float* wp = (float*)&wq;
    #pragma unroll
    for (int j = 0; j < 4; j++) {
      const float w2 = e2[g * 4 + j] * inv2;
      wp[j] = w2;
      ((unsigned short*)&bq)[j] = f2bf(w2);
    }
    if (mq + 3 < M_DIM) *(float4*)&wout[(size_t)b * M_DIM + mq] = wq;
    *(ushort4*)&wbf[(size_t)b * M_PAD + mq] = bq;   // padded cols exact 0
  }
}

// ---------------- GEMM2: C[b][n] = sum_k Wbf[b][k] * mem[k][n] (2-phase pipelined) --
// BM=256, BN=64, BK=64, 512 n-tiles. W via cp_async16 (swizzled, dbuf). B:
// thread owns col n=t&63, k-group kc=t>>6: 16 coalesced fp32 column loads
// prefetched to regs -> bf16 pack -> 2 swizzled ds_write_b128 (conflict-free).
// OOB k rows (>= M_DIM) clamped to row 0: W is exact-0 there, product = 0.
__global__ __launch_bounds__(256, 2) void gemm2_kernel(const unsigned short* __restrict__ W,
                                                       const float* __restrict__ mem,
                                                       float* __restrict__ C) {
  __shared__ __align__(16) unsigned short Wsm[2][256 * 64];  // 64 KB dbuf, swizzled
  __shared__ __align__(16) unsigned short Bt[64 * 64];       // 8 KB, [n][k] swizzled
  const int t = threadIdx.x;
  const int n0 = blockIdx.x * 64;
  const int wid = t >> 6, lane = t & 63;
  const int lr = lane & 15, kq = lane >> 4;
  const int l8 = lane & 7, lrow = lane >> 3;

  const unsigned short* Wb = W + (size_t)(64 * wid + lrow) * M_PAD + (l8 ^ lrow) * 8;

  const int bn = t & 63;                 // column within n-tile
  const int kc = t >> 6;                 // 0..3 k-group (wave-uniform)
  const float* Bg2 = mem + n0 + bn;

  f32x4 acc[4][4] = {};

  // prologue: stage tile 0
  #pragma unroll
  for (int i = 0; i < 8; i++)
    cp_async16(Wb + (size_t)(8 * i) * M_PAD, &Wsm[0][(64 * wid + 8 * i) * 64]);
  float bv[16];
  #pragma unroll
  for (int j = 0; j < 16; j++) {
    const int k = kc * 16 + j;           // < 64 -> always valid at k0=0
    bv[j] = Bg2[(size_t)k * D_DIM];
  }

  int cur = 0;
  const int NT = M_PAD / 64;             // 32
  for (int it = 0; it < NT; it++) {
    // phase 1: convert current B regs -> Bt (swizzled, conflict-free)
    bf16x8 kb0, kb1;
    #pragma unroll
    for (int j = 0; j < 8; j++) kb0[j] = (short)f2bf(bv[j]);
    #pragma unroll
    for (int j = 0; j < 8; j++) kb1[j] = (short)f2bf(bv[8 + j]);
    *(bf16x8*)&Bt[bn * 64 + (((kc * 2 + 0) ^ (bn & 7)) * 8)] = kb0;
    *(bf16x8*)&Bt[bn * 64 + (((kc * 2 + 1) ^ (bn & 7)) * 8)] = kb1;
    __syncthreads();   // mid: Bt visible; Wsm[cur] complete (vmcnt drained)

    // phase 2a: issue next-tile prefetch (drains at END-of-iter barrier,
    // hidden under the compute below)
    float bvn[16];
    if (it + 1 < NT) {
      const int kn = it * 64 + 64;
      #pragma unroll
      for (int i = 0; i < 8; i++)
        cp_async16(Wb + kn + (size_t)(8 * i) * M_PAD, &Wsm[cur ^ 1][(64 * wid + 8 * i) * 64]);
      #pragma unroll
      for (int j = 0; j < 16; j++) {
        const int k = kn + kc * 16 + j;
        const int r = (k < M_DIM) ? k : 0;   // clamp: W[k>=M_DIM] == 0 exactly
        bvn[j] = Bg2[(size_t)r * D_DIM];
      }
    }

    // phase 2b: compute from Wsm[cur], Bt
    bf16x8 bfr[2][4];
    #pragma unroll
    for (int h = 0; h < 2; h++)
      #pragma unroll
      for (int ni = 0; ni < 4; ni++)
        bfr[h][ni] = *(const bf16x8*)&Bt[(ni * 16 + lr) * 64 + (((h * 4 + kq) ^ (lr & 7)) * 8)];
    #pragma unroll
    for (int mi = 0; mi < 4; mi++) {
      #pragma unroll
      for (int h = 0; h < 2; h++) {
        const int sw = ((h * 4 + kq) ^ (lr & 7)) * 8;
        const bf16x8 af = *(const bf16x8*)&Wsm[cur][(wid * 64 + mi * 16 + lr) * 64 + sw];
        #pragma unroll
        for (int ni = 0; ni < 4; ni++)
          acc[mi][ni] = __builtin_amdgcn_mfma_f32_16x16x32_bf16(af, bfr[h][ni], acc[mi][ni], 0, 0, 0);
      }
    }
    __syncthreads();   // end: prefetch drained (hidden under compute); all
                       // Bt/Wsm[cur] reads done before next iter's overwrite
    if (it + 1 < NT) {
      #pragma unroll
      for (int j = 0; j < 16; j++) bv[j] = bvn[j];
    }
    cur ^= 1;
  }
  #pragma unroll
  for (int mi = 0; mi < 4; mi++) {
    const int b0 = wid * 64 + mi * 16 + kq * 4;
    #pragma unroll
    for (int ni = 0; ni < 4; ni++) {
      const int col = n0 + ni * 16 + lr;
      #pragma unroll
      for (int j = 0; j < 4; j++)
        C[(size_t)(b0 + j) * D_DIM + col] = acc[mi][ni][j];
    }
  }
}

// ---------------- launch ----------------
extern "C" void kernel_launch(void* const* d_in, const int* in_sizes, int n_in,
                              void* d_out, int out_size, void* d_ws, size_t ws_size,
                              hipStream_t stream) {
  const float* feature = (const float*)d_in[0];   // [256][32768]
  const float* memory  = (const float*)d_in[1];   // [2000][32768]
  float* out_feat = (float*)d_out;                         // [256][32768]
  float* out_w = out_feat + (size_t)B_DIM * D_DIM;         // [256][2000]

  char* ws = (char*)d_ws;
  unsigned short* F16 = (unsigned short*)ws;                   // [256][32768] bf16 (16 MB)
  float* Spart        = (float*)(ws + 16777216ull);            // [16][256][2048] fp32 (33.5 MB)
  unsigned short* Wbf = (unsigned short*)(ws + 50331648ull);   // [256][2048] bf16 (1 MB)
  float* rnm_sq       = (float*)(ws + 51380224ull);            // [2048]
  float* rnf          = (float*)(ws + 51388416ull);            // [256]

  zero_kernel<<<(M_PAD + 255) / 256, 256, 0, stream>>>(rnm_sq, M_PAD);
  prep_feat_kernel<<<B_DIM, 256, 0, stream>>>(feature, F16, rnf);
  gemm1_fused<<<dim3(M_PAD / 64, NS1), 256, 0, stream>>>(F16, memory, Spart, rnm_sq);
  softmax_kernel<<<B_DIM, 256, 0, stream>>>(Spart, rnf, rnm_sq, out_w, Wbf);
  gemm2_kernel<<<D_DIM / 64, 256, 0, stream>>>(Wbf, memory, out_feat);
}

// Round 4
// 488.597 us; speedup vs baseline: 1.0080x; 1.0080x over previous
//
#include <hip/hip_runtime.h>
#include <math.h>

// MemoryUnit: fn=l2norm(feature), mn=l2norm(memory), S=fn.mn^T -> softmax ->
// hardshrink(0.0005) -> softmax -> w ; mem_feat = w @ memory.
// Round 9: traffic reduction (the round-3 null proved the GEMMs are BW-bound,
// not latency-bound; pipeline restructure moved nothing).
//  - Spart stored as bf16 (was fp32): -100 MB HBM (-50 write in gemm1,
//    -50 read in softmax). S-perturbation ~1e-5, an order below existing
//    bf16-MFMA input rounding; hard-shrink flips change softmax-2 by only
//    e^+-5e-4 => ~2.5e-7 on w. Accumulation across the 16 splits stays fp32.
//  - gemm1 grid flattened to 1-D 512 with XCD-aware decode: xcd=bid&7 owns
//    k-splits {2*xcd, 2*xcd+1}; its 64 blocks share 2 MB of F16 slabs in the
//    XCD-private L2 (vs all 16 slabs through L3/HBM). Bijective (512=8*64).
//  - K-loop structure unchanged from the verified round-3 kernel (2-phase,
//    full __syncthreads, cp_async dbuf A, reg-prefetch B).

#define D_DIM 32768
#define B_DIM 256
#define M_DIM 2000
#define M_PAD 2048
#define NS1 16
#define KSLAB (D_DIM / NS1)   // 2048
#define LAM 0.0005f
#define LDB 72                // padded LDS stride (ushorts) for gemm1 B tile

typedef __attribute__((ext_vector_type(8))) short bf16x8;   // 8 bf16 = 4 VGPR
typedef __attribute__((ext_vector_type(4))) float f32x4;

#define GLOBAL_AS __attribute__((address_space(1)))
#define LDS_AS __attribute__((address_space(3)))

__device__ __forceinline__ void cp_async16(const void* g, void* l) {
  // 64 lanes x 16B -> LDS base + lane*16 (wave-uniform lds base required)
  __builtin_amdgcn_global_load_lds((const GLOBAL_AS unsigned int*)g,
                                   (LDS_AS unsigned int*)l, 16, 0, 0);
}

__device__ __forceinline__ unsigned short f2bf(float f) {
  union { float f; unsigned u; } v; v.f = f;
  unsigned r = v.u + 0x7FFFu + ((v.u >> 16) & 1u);  // RNE
  return (unsigned short)(r >> 16);
}

__device__ __forceinline__ float bf2f(unsigned short h) {
  union { unsigned u; float f; } v; v.u = ((unsigned)h) << 16;
  return v.f;
}

// ---------------- zero (for rnm_sq atomics) ----------------
__global__ __launch_bounds__(256) void zero_kernel(float* __restrict__ p, int n) {
  int i = blockIdx.x * 256 + threadIdx.x;
  if (i < n) p[i] = 0.f;
}

// ---------------- prep feature: fp32 -> bf16 + 1/max(||x||,eps) ----------------
__global__ __launch_bounds__(256) void prep_feat_kernel(const float* __restrict__ src,
                                                        unsigned short* __restrict__ dst,
                                                        float* __restrict__ rn_inv) {
  const size_t row = blockIdx.x;
  const int t = threadIdx.x;
  const float4* p = (const float4*)(src + row * (size_t)D_DIM);
  ushort4* q = (ushort4*)(dst + row * (size_t)D_DIM);
  float s = 0.f;
  for (int i = t; i < D_DIM / 4; i += 256) {
    float4 v = p[i];
    s = fmaf(v.x, v.x, s); s = fmaf(v.y, v.y, s);
    s = fmaf(v.z, v.z, s); s = fmaf(v.w, v.w, s);
    ushort4 b; b.x = f2bf(v.x); b.y = f2bf(v.y); b.z = f2bf(v.z); b.w = f2bf(v.w);
    q[i] = b;
  }
  #pragma unroll
  for (int off = 32; off > 0; off >>= 1) s += __shfl_down(s, off, 64);
  __shared__ float partial[4];
  if ((t & 63) == 0) partial[t >> 6] = s;
  __syncthreads();
  if (t == 0) {
    float tt = partial[0] + partial[1] + partial[2] + partial[3];
    rn_inv[row] = 1.0f / fmaxf(sqrtf(tt), 1e-12f);
  }
}

// ---------------- fused GEMM1 + memory norm (2-phase pipelined) ----------------
// 1-D grid 512, XCD-decoded: xcd=bid&7, slot=bid>>3; split=xcd*2+(slot>=32),
// mtile=slot&31. A = F16 (cp_async16, swizzled unpadded LDS, double-buffered);
// B = memory fp32 prefetched to regs -> cvt bf16 -> padded LDS; sumsq
// accumulated. Spart written as bf16. All barriers full __syncthreads().
__global__ __launch_bounds__(256, 2) void gemm1_fused(const unsigned short* __restrict__ F16,
                                                      const float* __restrict__ mem,
                                                      unsigned short* __restrict__ Spart,
                                                      float* __restrict__ rnm_sq) {
  __shared__ __align__(16) unsigned short Asm[2][256 * 64];   // 64 KB dbuf, swizzled
  __shared__ __align__(16) unsigned short Bsm[64 * LDB];      // 9 KB, padded
  const int t = threadIdx.x;
  // XCD-aware decode: blocks with the same split co-locate on one XCD so the
  // 1 MB F16 slab stays in that XCD's private L2.
  const int bid = blockIdx.x;
  const int xcd = bid & 7, slot = bid >> 3;
  const int ysplit = xcd * 2 + (slot >> 5);   // 0..15
  const int m0 = (slot & 31) * 64;
  const int kbase = ysplit * KSLAB;
  const int wid = t >> 6, lane = t & 63;
  const int lr = lane & 15, kq = lane >> 4;
  const int l8 = lane & 7, lrow = lane >> 3;

  // B staging: thread handles row (t>>2), 16 floats at col (t&3)*16
  const int brow = t >> 2;
  const int bcol = (t & 3) * 16;
  const int gm = m0 + brow;
  const bool bvalid = gm < M_DIM;
  // OOB rows clamped to row 0: products land in S columns >= M_DIM (masked in
  // softmax) and ss is discarded (atomicAdd guarded by bvalid).
  const float* Bg = mem + (size_t)(bvalid ? gm : 0) * D_DIM + kbase + bcol;

  const unsigned short* Ab = F16 + (size_t)(64 * wid + lrow) * D_DIM + kbase + (l8 ^ lrow) * 8;

  f32x4 acc[4][4] = {};
  float ss = 0.f;

  // prologue: stage tile 0 (exposed latency once; drains at iter-0 mid barrier
  // / the v-reg use in convert)
  #pragma unroll
  for (int i = 0; i < 8; i++)
    cp_async16(Ab + (size_t)(8 * i) * D_DIM, &Asm[0][(64 * wid + 8 * i) * 64]);
  float4 v[4];
  #pragma unroll
  for (int j = 0; j < 4; j++) v[j] = *(const float4*)(Bg + 4 * j);

  int cur = 0;
  const int NT = KSLAB / 64;          // 32
  for (int kt = 0; kt < NT; kt++) {
    // phase 1: convert current B regs -> Bsm (+ sumsq)
    #pragma unroll
    for (int j = 0; j < 4; j++) {
      ss = fmaf(v[j].x, v[j].x, ss); ss = fmaf(v[j].y, v[j].y, ss);
      ss = fmaf(v[j].z, v[j].z, ss); ss = fmaf(v[j].w, v[j].w, ss);
      ushort4 c; c.x = f2bf(v[j].x); c.y = f2bf(v[j].y);
      c.z = f2bf(v[j].z); c.w = f2bf(v[j].w);
      *(ushort4*)&Bsm[brow * LDB + bcol + 4 * j] = c;
    }
    __syncthreads();   // mid: Bsm visible; Asm[cur] complete (vmcnt drained);
                       // nothing else in flight at this point

    // phase 2a: issue next-tile prefetch AFTER the barrier so it drains at the
    // END-of-iter barrier -- hidden under the ds_read+MFMA phase below.
    float4 vn[4];
    if (kt + 1 < NT) {
      const int kk = (kt + 1) * 64;
      #pragma unroll
      for (int i = 0; i < 8; i++)
        cp_async16(Ab + kk + (size_t)(8 * i) * D_DIM, &Asm[cur ^ 1][(64 * wid + 8 * i) * 64]);
      #pragma unroll
      for (int j = 0; j < 4; j++) vn[j] = *(const float4*)(Bg + kk + 4 * j);
    }

    // phase 2b: compute from Asm[cur], Bsm
    bf16x8 bfr[2][4];
    #pragma unroll
    for (int h = 0; h < 2; h++)
      #pragma unroll
      for (int ni = 0; ni < 4; ni++)
        bfr[h][ni] = *(const bf16x8*)&Bsm[(ni * 16 + lr) * LDB + h * 32 + kq * 8];
    #pragma unroll
    for (int mi = 0; mi < 4; mi++) {
      #pragma unroll
      for (int h = 0; h < 2; h++) {
        const int sw = ((h * 4 + kq) ^ (lr & 7)) * 8;
        const bf16x8 af = *(const bf16x8*)&Asm[cur][(wid * 64 + mi * 16 + lr) * 64 + sw];
        #pragma unroll
        for (int ni = 0; ni < 4; ni++)
          acc[mi][ni] = __builtin_amdgcn_mfma_f32_16x16x32_bf16(af, bfr[h][ni], acc[mi][ni], 0, 0, 0);
      }
    }
    __syncthreads();   // end: prefetch drained (hidden under compute); all
                       // Bsm/Asm[cur] reads done before next iter's overwrite
    if (kt + 1 < NT) {
      #pragma unroll
      for (int j = 0; j < 4; j++) v[j] = vn[j];
    }
    cur ^= 1;
  }

  // sumsq: 4 threads share a row
  ss += __shfl_down(ss, 2, 4);
  ss += __shfl_down(ss, 1, 4);
  if ((t & 3) == 0 && bvalid) atomicAdd(&rnm_sq[gm], ss);

  // Spart[split][b][m] (bf16); C/D layout col=lane&15, row=(lane>>4)*4+j
  unsigned short* Sp = Spart + (size_t)ysplit * (B_DIM * M_PAD);
  #pragma unroll
  for (int mi = 0; mi < 4; mi++) {
    const int b0 = wid * 64 + mi * 16 + kq * 4;
    #pragma unroll
    for (int ni = 0; ni < 4; ni++) {
      const int col = m0 + ni * 16 + lr;
      #pragma unroll
      for (int j = 0; j < 4; j++)
        Sp[(size_t)(b0 + j) * M_PAD + col] = f2bf(acc[mi][ni][j]);
    }
  }
}

// ---------------- softmax: reduce splits -> scale -> softmax -> shrink -> softmax ----
__device__ __forceinline__ float block_reduce(float x, bool is_max, float* red,
                                              int wid, int lane) {
  #pragma unroll
  for (int off = 32; off > 0; off >>= 1) {
    float o = __shfl_down(x, off, 64);
    x = is_max ? fmaxf(x, o) : (x + o);
  }
  __syncthreads();
  if (lane == 0) red[wid] = x;
  __syncthreads();
  return is_max ? fmaxf(fmaxf(red[0], red[1]), fmaxf(red[2], red[3]))
                : (red[0] + red[1] + red[2] + red[3]);
}

__global__ __launch_bounds__(256) void softmax_kernel(const unsigned short* __restrict__ Spart,
                                                      const float* __restrict__ rnf,
                                                      const float* __restrict__ rnm_sq,
                                                      float* __restrict__ wout,
                                                      unsigned short* __restrict__ wbf) {
  const int b = blockIdx.x;
  const int t = threadIdx.x;
  const int wid = t >> 6, lane = t & 63;
  const float sf = rnf[b];
  __shared__ float red[4];

  float v[8];
  #pragma unroll
  for (int g = 0; g < 2; g++) {
    const int mq = g * 1024 + 4 * t;             // quad base (quads never straddle M_DIM: 2000=4*500)
    float a0 = 0.f, a1 = 0.f, a2 = 0.f, a3 = 0.f;
    #pragma unroll
    for (int s = 0; s < NS1; s++) {
      const ushort4 u = *(const ushort4*)&Spart[(size_t)s * (B_DIM * M_PAD) + (size_t)b * M_PAD + mq];
      a0 += bf2f(u.x); a1 += bf2f(u.y); a2 += bf2f(u.z); a3 += bf2f(u.w);
    }
    const float aa[4] = {a0, a1, a2, a3};
    #pragma unroll
    for (int j = 0; j < 4; j++) {
      const int m = mq + j;
      const float msc = 1.0f / fmaxf(sqrtf(rnm_sq[m]), 1e-12f);
      v[g * 4 + j] = (m < M_DIM) ? aa[j] * (sf * msc) : -INFINITY;
    }
  }
  float mx = v[0];
  #pragma unroll
  for (int i = 1; i < 8; i++) mx = fmaxf(mx, v[i]);
  mx = block_reduce(mx, true, red, wid, lane);

  float e[8]; float sum = 0.f;
  #pragma unroll
  for (int i = 0; i < 8; i++) { e[i] = expf(v[i] - mx); sum += e[i]; }
  sum = block_reduce(sum, false, red, wid, lane);
  const float inv = 1.f / sum;

  float s2[8];
  #pragma unroll
  for (int i = 0; i < 8; i++) {
    float w1 = e[i] * inv;
    s2[i] = (w1 > LAM) ? w1 : 0.f;
  }
  float mx2 = 0.f;
  #pragma unroll
  for (int i = 0; i < 8; i++) mx2 = fmaxf(mx2, s2[i]);
  mx2 = block_reduce(mx2, true, red, wid, lane);

  float e2[8]; float sum2 = 0.f;
  #pragma unroll
  for (int g = 0; g < 2; g++)
    #pragma unroll
    for (int j = 0; j < 4; j++) {
      const int i = g * 4 + j;
      const int m = g * 1024 + 4 * t + j;
      e2[i] = (m < M_DIM) ? expf(s2[i] - mx2) : 0.f;
      sum2 += e2[i];
    }
  sum2 = block_reduce(sum2, false, red, wid, lane);
  const float inv2 = 1.f / sum2;

  #pragma unroll
  for (int g = 0; g < 2; g++) {
    const int mq = g * 1024 + 4 * t;
    float4 wq; ushort4 bq;
    float* wp = (float*)&wq;
    #pragma unroll
    for (int j = 0; j < 4; j++) {
      const float w2 = e2[g * 4 + j] * inv2;
      wp[j] = w2;
      ((unsigned short*)&bq)[j] = f2bf(w2);
    }
    if (mq + 3 < M_DIM) *(float4*)&wout[(size_t)b * M_DIM + mq] = wq;
    *(ushort4*)&wbf[(size_t)b * M_PAD + mq] = bq;   // padded cols exact 0
  }
}

// ---------------- GEMM2: C[b][n] = sum_k Wbf[b][k] * mem[k][n] (2-phase pipelined) --
// BM=256, BN=64, BK=64, 512 n-tiles. W via cp_async16 (swizzled, dbuf). B:
// thread owns col n=t&63, k-group kc=t>>6: 16 coalesced fp32 column loads
// prefetched to regs -> bf16 pack -> 2 swizzled ds_write_b128 (conflict-free).
// OOB k rows (>= M_DIM) clamped to row 0: W is exact-0 there, product = 0.
__global__ __launch_bounds__(256, 2) void gemm2_kernel(const unsigned short* __restrict__ W,
                                                       const float* __restrict__ mem,
                                                       float* __restrict__ C) {
  __shared__ __align__(16) unsigned short Wsm[2][256 * 64];  // 64 KB dbuf, swizzled
  __shared__ __align__(16) unsigned short Bt[64 * 64];       // 8 KB, [n][k] swizzled
  const int t = threadIdx.x;
  const int n0 = blockIdx.x * 64;
  const int wid = t >> 6, lane = t & 63;
  const int lr = lane & 15, kq = lane >> 4;
  const int l8 = lane & 7, lrow = lane >> 3;

  const unsigned short* Wb = W + (size_t)(64 * wid + lrow) * M_PAD + (l8 ^ lrow) * 8;

  const int bn = t & 63;                 // column within n-tile
  const int kc = t >> 6;                 // 0..3 k-group (wave-uniform)
  const float* Bg2 = mem + n0 + bn;

  f32x4 acc[4][4] = {};

  // prologue: stage tile 0
  #pragma unroll
  for (int i = 0; i < 8; i++)
    cp_async16(Wb + (size_t)(8 * i) * M_PAD, &Wsm[0][(64 * wid + 8 * i) * 64]);
  float bv[16];
  #pragma unroll
  for (int j = 0; j < 16; j++) {
    const int k = kc * 16 + j;           // < 64 -> always valid at k0=0
    bv[j] = Bg2[(size_t)k * D_DIM];
  }

  int cur = 0;
  const int NT = M_PAD / 64;             // 32
  for (int it = 0; it < NT; it++) {
    // phase 1: convert current B regs -> Bt (swizzled, conflict-free)
    bf16x8 kb0, kb1;
    #pragma unroll
    for (int j = 0; j < 8; j++) kb0[j] = (short)f2bf(bv[j]);
    #pragma unroll
    for (int j = 0; j < 8; j++) kb1[j] = (short)f2bf(bv[8 + j]);
    *(bf16x8*)&Bt[bn * 64 + (((kc * 2 + 0) ^ (bn & 7)) * 8)] = kb0;
    *(bf16x8*)&Bt[bn * 64 + (((kc * 2 + 1) ^ (bn & 7)) * 8)] = kb1;
    __syncthreads();   // mid: Bt visible; Wsm[cur] complete (vmcnt drained)

    // phase 2a: issue next-tile prefetch (drains at END-of-iter barrier,
    // hidden under the compute below)
    float bvn[16];
    if (it + 1 < NT) {
      const int kn = it * 64 + 64;
      #pragma unroll
      for (int i = 0; i < 8; i++)
        cp_async16(Wb + kn + (size_t)(8 * i) * M_PAD, &Wsm[cur ^ 1][(64 * wid + 8 * i) * 64]);
      #pragma unroll
      for (int j = 0; j < 16; j++) {
        const int k = kn + kc * 16 + j;
        const int r = (k < M_DIM) ? k : 0;   // clamp: W[k>=M_DIM] == 0 exactly
        bvn[j] = Bg2[(size_t)r * D_DIM];
      }
    }

    // phase 2b: compute from Wsm[cur], Bt
    bf16x8 bfr[2][4];
    #pragma unroll
    for (int h = 0; h < 2; h++)
      #pragma unroll
      for (int ni = 0; ni < 4; ni++)
        bfr[h][ni] = *(const bf16x8*)&Bt[(ni * 16 + lr) * 64 + (((h * 4 + kq) ^ (lr & 7)) * 8)];
    #pragma unroll
    for (int mi = 0; mi < 4; mi++) {
      #pragma unroll
      for (int h = 0; h < 2; h++) {
        const int sw = ((h * 4 + kq) ^ (lr & 7)) * 8;
        const bf16x8 af = *(const bf16x8*)&Wsm[cur][(wid * 64 + mi * 16 + lr) * 64 + sw];
        #pragma unroll
        for (int ni = 0; ni < 4; ni++)
          acc[mi][ni] = __builtin_amdgcn_mfma_f32_16x16x32_bf16(af, bfr[h][ni], acc[mi][ni], 0, 0, 0);
      }
    }
    __syncthreads();   // end: prefetch drained (hidden under compute); all
                       // Bt/Wsm[cur] reads done before next iter's overwrite
    if (it + 1 < NT) {
      #pragma unroll
      for (int j = 0; j < 16; j++) bv[j] = bvn[j];
    }
    cur ^= 1;
  }
  #pragma unroll
  for (int mi = 0; mi < 4; mi++) {
    const int b0 = wid * 64 + mi * 16 + kq * 4;
    #pragma unroll
    for (int ni = 0; ni < 4; ni++) {
      const int col = n0 + ni * 16 + lr;
      #pragma unroll
      for (int j = 0; j < 4; j++)
        C[(size_t)(b0 + j) * D_DIM + col] = acc[mi][ni][j];
    }
  }
}

// ---------------- launch ----------------
extern "C" void kernel_launch(void* const* d_in, const int* in_sizes, int n_in,
                              void* d_out, int out_size, void* d_ws, size_t ws_size,
                              hipStream_t stream) {
  const float* feature = (const float*)d_in[0];   // [256][32768]
  const float* memory  = (const float*)d_in[1];   // [2000][32768]
  float* out_feat = (float*)d_out;                         // [256][32768]
  float* out_w = out_feat + (size_t)B_DIM * D_DIM;         // [256][2000]

  char* ws = (char*)d_ws;
  unsigned short* F16 = (unsigned short*)ws;                   // [256][32768] bf16 (16 MB)
  unsigned short* Spart = (unsigned short*)(ws + 16777216ull); // [16][256][2048] bf16 (16.8 MB)
  unsigned short* Wbf = (unsigned short*)(ws + 50331648ull);   // [256][2048] bf16 (1 MB)
  float* rnm_sq       = (float*)(ws + 51380224ull);            // [2048]
  float* rnf          = (float*)(ws + 51388416ull);            // [256]

  zero_kernel<<<(M_PAD + 255) / 256, 256, 0, stream>>>(rnm_sq, M_PAD);
  prep_feat_kernel<<<B_DIM, 256, 0, stream>>>(feature, F16, rnf);
  gemm1_fused<<<512, 256, 0, stream>>>(F16, memory, Spart, rnm_sq);
  softmax_kernel<<<B_DIM, 256, 0, stream>>>(Spart, rnf, rnm_sq, out_w, Wbf);
  gemm2_kernel<<<D_DIM / 64, 256, 0, stream>>>(Wbf, memory, out_feat);
}